// Round 4
// baseline (1011.708 us; speedup 1.0000x reference)
//
#include <hip/hip_runtime.h>

// Shapes (fixed by the problem)
#define BB 8
#define SS 2048
#define FF 1024
#define DD 512
// M = BB*SS = 16384 rows for the QKV GEMMs

typedef __attribute__((ext_vector_type(4))) float f32x4;
typedef __attribute__((ext_vector_type(8))) short s16x8;
typedef __attribute__((ext_vector_type(4))) short s16x4;

__device__ __forceinline__ unsigned short f2bf(float f) {
  unsigned int u = __builtin_bit_cast(unsigned int, f);
  unsigned int r = ((u >> 16) & 1u) + 0x7fffu;
  return (unsigned short)((u + r) >> 16);
}

__device__ __forceinline__ void async16(const void* g, void* l) {
  __builtin_amdgcn_global_load_lds((const __attribute__((address_space(1))) void*)g,
                                   (__attribute__((address_space(3))) void*)l, 16, 0, 0);
}

// ---------------------------------------------------------------------------
// Kernel 0: x fp32 -> bf16 (for MFMA) + passthrough copy into out[:, :1024]
// ---------------------------------------------------------------------------
__global__ __launch_bounds__(256) void convert_x(const float* __restrict__ x,
                                                 float* __restrict__ out,
                                                 unsigned short* __restrict__ xb) {
  size_t idx = ((size_t)blockIdx.x * 256 + threadIdx.x) * 4;  // 16384*1024 elems total
  f32x4 v = *(const f32x4*)(x + idx);
  size_t row = idx >> 10;        // / 1024
  size_t col = idx & 1023;
  *(f32x4*)(out + row * 1536 + col) = v;
  s16x4 h;
  h[0] = (short)f2bf(v[0]); h[1] = (short)f2bf(v[1]);
  h[2] = (short)f2bf(v[2]); h[3] = (short)f2bf(v[3]);
  *(s16x4*)(xb + idx) = h;
}

// ---------------------------------------------------------------------------
// Kernel 1: transpose+convert the 3 weights [1024][512] f32 -> Wt bf16 [512][1024]
// ---------------------------------------------------------------------------
__global__ __launch_bounds__(256) void prep_w(const float* __restrict__ Wq,
                                              const float* __restrict__ Wk,
                                              const float* __restrict__ Wv,
                                              unsigned short* __restrict__ wt) {
  int z = blockIdx.z;
  const float* W = (z == 0) ? Wq : ((z == 1) ? Wk : Wv);
  unsigned short* o = wt + (size_t)z * DD * FF;
  __shared__ __align__(16) float t[32][33];
  int k0 = blockIdx.x * 32, n0 = blockIdx.y * 32;
  int tid = threadIdx.x;
  int r = tid >> 3, c4 = (tid & 7) * 4;
  f32x4 v = *(const f32x4*)(W + (size_t)(k0 + r) * DD + n0 + c4);
  t[r][c4 + 0] = v[0]; t[r][c4 + 1] = v[1]; t[r][c4 + 2] = v[2]; t[r][c4 + 3] = v[3];
  __syncthreads();
  s16x4 h;
  h[0] = (short)f2bf(t[c4 + 0][r]);
  h[1] = (short)f2bf(t[c4 + 1][r]);
  h[2] = (short)f2bf(t[c4 + 2][r]);
  h[3] = (short)f2bf(t[c4 + 3][r]);
  *(s16x4*)(o + (size_t)(n0 + r) * FF + k0 + c4) = h;
}

// ---------------------------------------------------------------------------
// Kernel 2: GEMM (m97 structure): C[16384][512] = xb[16384][1024] @ W + bias
//   128x128 tile, BK=32, 4 waves (2x2), global_load_lds width 16.
//   z=0: q (scaled by log2e/sqrt(512)), z=1: k, z=2: v stored TRANSPOSED [B][512][S]
//   v epilogue: per-wave LDS transpose -> 16B coalesced stores (was scattered u16).
// ---------------------------------------------------------------------------
__global__ __launch_bounds__(256, 2) void gemm_qkv(
    const unsigned short* __restrict__ xb, const unsigned short* __restrict__ wt,
    const float* __restrict__ bq, const float* __restrict__ bk, const float* __restrict__ bv,
    unsigned short* __restrict__ qo, unsigned short* __restrict__ ko,
    unsigned short* __restrict__ vto) {
  const int wsel = blockIdx.z;
  const unsigned short* W = wt + (size_t)wsel * DD * FF;
  const float* bias = (wsel == 0) ? bq : ((wsel == 1) ? bk : bv);
  const int m0 = blockIdx.x * 128, n0 = blockIdx.y * 128;

  // union: main loop uses Al(8K)+Bl(8K); v-epilogue reuses as 4x64x72 u16 transpose buf
  __shared__ __align__(16) char smem[36864];
  unsigned short* Al = (unsigned short*)smem;
  unsigned short* Bl = (unsigned short*)(smem + 8192);

  const int tid = threadIdx.x;
  const int lane = tid & 63, wv = tid >> 6;
  const int wr = wv >> 1, wc = wv & 1;
  const int l15 = lane & 15, lg = lane >> 4;

  const f32x4 fzero = {0.f, 0.f, 0.f, 0.f};
  f32x4 acc[4][4];
#pragma unroll
  for (int i = 0; i < 4; ++i)
#pragma unroll
    for (int j = 0; j < 4; ++j) acc[i][j] = fzero;

  for (int k0 = 0; k0 < FF; k0 += 32) {
#pragma unroll
    for (int is = 0; is < 2; ++is) {
      int chunk = (is * 4 + wv) * 64;       // 64 lane-16B units
      int lin = (chunk + lane) * 8;         // elements
      int r = lin >> 5, c = lin & 31;
      async16(xb + (size_t)(m0 + r) * FF + k0 + c, (char*)Al + (size_t)chunk * 16);
      async16(W + (size_t)(n0 + r) * FF + k0 + c, (char*)Bl + (size_t)chunk * 16);
    }
    __syncthreads();
    s16x8 af[4], bf[4];
#pragma unroll
    for (int mi = 0; mi < 4; ++mi)
      af[mi] = *(const s16x8*)(&Al[(wr * 64 + mi * 16 + l15) * 32 + lg * 8]);
#pragma unroll
    for (int ni = 0; ni < 4; ++ni)
      bf[ni] = *(const s16x8*)(&Bl[(wc * 64 + ni * 16 + l15) * 32 + lg * 8]);
#pragma unroll
    for (int mi = 0; mi < 4; ++mi)
#pragma unroll
      for (int ni = 0; ni < 4; ++ni)
        acc[mi][ni] = __builtin_amdgcn_mfma_f32_16x16x32_bf16(af[mi], bf[ni], acc[mi][ni], 0, 0, 0);
    __syncthreads();
  }

  const float QS = 0.0637583894f;  // (1/sqrt(512)) * log2(e)
  if (wsel == 2) {
    // transpose 64x64 wave tile through per-wave LDS, then 16B coalesced stores
    unsigned short* Tw = (unsigned short*)smem + (size_t)wv * 64 * 72;
#pragma unroll
    for (int ni = 0; ni < 4; ++ni) {
      int cl = ni * 16 + l15;
      float bvv = bias[n0 + wc * 64 + cl];
#pragma unroll
      for (int mi = 0; mi < 4; ++mi)
#pragma unroll
        for (int j = 0; j < 4; ++j)
          Tw[cl * 72 + mi * 16 + lg * 4 + j] = f2bf(acc[mi][ni][j] + bvv);
    }
    asm volatile("s_waitcnt lgkmcnt(0)" ::: "memory");
    const int bb = (m0 + wr * 64) >> 11;       // batch (64-row tile never straddles)
    const int sb = (m0 + wr * 64) & 2047;      // seq base
    const int cb = n0 + wc * 64;               // d base
#pragma unroll
    for (int p = 0; p < 8; ++p) {
      int cl = p * 8 + (lane >> 3);
      int sl = (lane & 7) * 8;
      s16x8 vv = *(const s16x8*)(Tw + cl * 72 + sl);
      *(s16x8*)(vto + ((size_t)(bb * DD + cb + cl)) * SS + sb + sl) = vv;
    }
  } else {
    unsigned short* o = wsel ? ko : qo;
#pragma unroll
    for (int ni = 0; ni < 4; ++ni) {
      int cg = n0 + wc * 64 + ni * 16 + l15;
      float bvv = bias[cg];
#pragma unroll
      for (int mi = 0; mi < 4; ++mi) {
#pragma unroll
        for (int j = 0; j < 4; ++j) {
          int rg = m0 + wr * 64 + mi * 16 + lg * 4 + j;
          float val = acc[mi][ni][j] + bvv;
          if (wsel == 0) val *= QS;
          o[(size_t)rg * DD + cg] = f2bf(val);
        }
      }
    }
  }
}

// ---------------------------------------------------------------------------
// Kernel 3: causal flash attention — v2: NO LDS staging (K/V tiles are L2/L3
//   resident), 1-wave blocks, zero __syncthreads, longest-first dispatch.
//   Grid (128, 8, 2): x -> 16-row q-group (r16 = 127-x, longest first),
//   y -> batch, z -> which 256 of the 512 value-dims.
//   Per wave: Q[16][512] in regs, KVBLK=32, online softmax in exp2 domain
//   (scale folded into q at GEMM), P bounced via 1.3KB wave-private LDS.
// ---------------------------------------------------------------------------
__global__ __launch_bounds__(64) void attn(const unsigned short* __restrict__ qg,
                                           const unsigned short* __restrict__ kgl,
                                           const unsigned short* __restrict__ vtg,
                                           float* __restrict__ out) {
  const int r16 = 127 - (int)blockIdx.x;   // longest blocks dispatch first
  const int b = blockIdx.y;
  const int vhalf = blockIdx.z;
  const int rowb0 = r16 * 16;

  __shared__ __align__(16) unsigned short Pl[16 * 40];  // 1280 B, wave-private

  const int lane = threadIdx.x & 63;
  const int l15 = lane & 15, lg = lane >> 4;

  // preload Q fragments (16 k-chunks of 32) — reused across up to 64 KV tiles
  s16x8 qf[16];
  {
    const unsigned short* qp = qg + ((size_t)(b * SS + rowb0 + l15)) * DD + lg * 8;
#pragma unroll
    for (int kk = 0; kk < 16; ++kk) qf[kk] = *(const s16x8*)(qp + kk * 32);
  }

  const f32x4 fzero = {0.f, 0.f, 0.f, 0.f};
  f32x4 oacc[16];
#pragma unroll
  for (int n = 0; n < 16; ++n) oacc[n] = fzero;
  float mrun[4], lrun[4];
#pragma unroll
  for (int i = 0; i < 4; ++i) { mrun[i] = -__builtin_inff(); lrun[i] = 0.f; }

  const unsigned short* kb = kgl + (size_t)b * SS * DD;
  const unsigned short* vb0 = vtg + ((size_t)(b * DD + vhalf * 256)) * SS;

  const int nt = (r16 >> 1) + 1;  // 32-key tiles covering keys <= rowb0+15
  for (int t = 0; t < nt; ++t) {
    const int kv0 = t * 32;

    // ---- S = Q @ K^T directly from global (L1/L2-hot)
    f32x4 s0 = fzero, s1 = fzero;
    const unsigned short* kp = kb + (size_t)(kv0 + l15) * DD + lg * 8;
#pragma unroll
    for (int kk = 0; kk < 16; ++kk) {
      s16x8 b0 = *(const s16x8*)(kp + kk * 32);
      s16x8 b1 = *(const s16x8*)(kp + 16 * DD + kk * 32);
      s0 = __builtin_amdgcn_mfma_f32_16x16x32_bf16(qf[kk], b0, s0, 0, 0, 0);
      s1 = __builtin_amdgcn_mfma_f32_16x16x32_bf16(qf[kk], b1, s1, 0, 0, 0);
    }

    // ---- causal mask (rows = rowb0+4*lg+i, cols = kv0 + {0,16} + l15)
    if (kv0 + 31 > rowb0) {
#pragma unroll
      for (int i = 0; i < 4; ++i) {
        int rg = rowb0 + lg * 4 + i;
        if (kv0 + l15 > rg)      s0[i] = -__builtin_inff();
        if (kv0 + 16 + l15 > rg) s1[i] = -__builtin_inff();
      }
    }

    // ---- online softmax (exp2 domain)
    float corr[4];
#pragma unroll
    for (int i = 0; i < 4; ++i) {
      float tm = fmaxf(s0[i], s1[i]);
      tm = fmaxf(tm, __shfl_xor(tm, 1));
      tm = fmaxf(tm, __shfl_xor(tm, 2));
      tm = fmaxf(tm, __shfl_xor(tm, 4));
      tm = fmaxf(tm, __shfl_xor(tm, 8));
      float mo = mrun[i];
      float mn = fmaxf(mo, tm);
      mrun[i] = mn;
      float c = __builtin_amdgcn_exp2f(mo - mn);
      float p0 = __builtin_amdgcn_exp2f(s0[i] - mn);
      float p1 = __builtin_amdgcn_exp2f(s1[i] - mn);
      float rs = p0 + p1;
      rs += __shfl_xor(rs, 1);
      rs += __shfl_xor(rs, 2);
      rs += __shfl_xor(rs, 4);
      rs += __shfl_xor(rs, 8);
      lrun[i] = lrun[i] * c + rs;
      corr[i] = c;
      Pl[(lg * 4 + i) * 40 + l15] = f2bf(p0);
      Pl[(lg * 4 + i) * 40 + 16 + l15] = f2bf(p1);
    }

    // ---- rescale O
#pragma unroll
    for (int n = 0; n < 16; ++n) {
      oacc[n][0] *= corr[0]; oacc[n][1] *= corr[1];
      oacc[n][2] *= corr[2]; oacc[n][3] *= corr[3];
    }

    // ---- PV: O += P @ V, V^T fragments straight from global
    asm volatile("s_waitcnt lgkmcnt(0)" ::: "memory");
    s16x8 pa = *(const s16x8*)(&Pl[l15 * 40 + lg * 8]);
#pragma unroll
    for (int n = 0; n < 16; ++n) {
      s16x8 vv = *(const s16x8*)(vb0 + (size_t)(n * 16 + l15) * SS + kv0 + lg * 8);
      oacc[n] = __builtin_amdgcn_mfma_f32_16x16x32_bf16(pa, vv, oacc[n], 0, 0, 0);
    }
  }

  // ---- epilogue: normalize and store to out[:, 1024 + vhalf*256 + ...]
  float inv[4];
#pragma unroll
  for (int i = 0; i < 4; ++i) inv[i] = 1.0f / lrun[i];
  size_t obase = ((size_t)(b * SS + rowb0 + lg * 4)) * 1536 + 1024 + vhalf * 256;
#pragma unroll
  for (int n = 0; n < 16; ++n) {
#pragma unroll
    for (int i = 0; i < 4; ++i) {
      out[obase + (size_t)i * 1536 + n * 16 + l15] = oacc[n][i] * inv[i];
    }
  }
}

// ---------------------------------------------------------------------------
// launch
// ---------------------------------------------------------------------------
extern "C" void kernel_launch(void* const* d_in, const int* in_sizes, int n_in,
                              void* d_out, int out_size, void* d_ws, size_t ws_size,
                              hipStream_t stream) {
  (void)in_sizes; (void)n_in; (void)out_size; (void)ws_size;
  const float* x  = (const float*)d_in[0];
  const float* Wq = (const float*)d_in[1];
  const float* bq = (const float*)d_in[2];
  const float* Wk = (const float*)d_in[3];
  const float* bk = (const float*)d_in[4];
  const float* Wv = (const float*)d_in[5];
  const float* bv = (const float*)d_in[6];
  float* out = (float*)d_out;

  // workspace layout (total ~83 MiB)
  char* ws = (char*)d_ws;
  unsigned short* xb  = (unsigned short*)(ws);                       // 16384*1024*2 = 32 MiB
  unsigned short* wt  = (unsigned short*)(ws + 33554432);            // 3*512*1024*2 = 3 MiB
  unsigned short* qw  = (unsigned short*)(ws + 33554432 + 3145728);  // 16 MiB
  unsigned short* kw  = qw + (size_t)16384 * 512;                    // 16 MiB
  unsigned short* vtw = kw + (size_t)16384 * 512;                    // 16 MiB (transposed [B][512][S])

  convert_x<<<16384, 256, 0, stream>>>(x, out, xb);
  prep_w<<<dim3(32, 16, 3), 256, 0, stream>>>(Wq, Wk, Wv, wt);
  gemm_qkv<<<dim3(128, 4, 3), 256, 0, stream>>>(xb, wt, bq, bk, bv, qw, kw, vtw);
  attn<<<dim3(128, 8, 2), 64, 0, stream>>>(qw, kw, vtw, out);
}

// Round 5
// 377.428 us; speedup vs baseline: 2.6805x; 2.6805x over previous
//
#include <hip/hip_runtime.h>

// Shapes (fixed by the problem)
#define BB 8
#define SS 2048
#define FF 1024
#define DD 512
// M = BB*SS = 16384 rows for the QKV GEMMs

typedef __attribute__((ext_vector_type(4))) float f32x4;
typedef __attribute__((ext_vector_type(8))) short s16x8;
typedef __attribute__((ext_vector_type(4))) short s16x4;

__device__ __forceinline__ unsigned short f2bf(float f) {
  unsigned int u = __builtin_bit_cast(unsigned int, f);
  unsigned int r = ((u >> 16) & 1u) + 0x7fffu;
  return (unsigned short)((u + r) >> 16);
}

__device__ __forceinline__ void async16(const void* g, void* l) {
  __builtin_amdgcn_global_load_lds((const __attribute__((address_space(1))) void*)g,
                                   (__attribute__((address_space(3))) void*)l, 16, 0, 0);
}

// ---------------------------------------------------------------------------
// Kernel 0: x fp32 -> bf16 (for MFMA) + passthrough copy into out[:, :1024]
// ---------------------------------------------------------------------------
__global__ __launch_bounds__(256) void convert_x(const float* __restrict__ x,
                                                 float* __restrict__ out,
                                                 unsigned short* __restrict__ xb) {
  size_t idx = ((size_t)blockIdx.x * 256 + threadIdx.x) * 4;  // 16384*1024 elems total
  f32x4 v = *(const f32x4*)(x + idx);
  size_t row = idx >> 10;        // / 1024
  size_t col = idx & 1023;
  *(f32x4*)(out + row * 1536 + col) = v;
  s16x4 h;
  h[0] = (short)f2bf(v[0]); h[1] = (short)f2bf(v[1]);
  h[2] = (short)f2bf(v[2]); h[3] = (short)f2bf(v[3]);
  *(s16x4*)(xb + idx) = h;
}

// ---------------------------------------------------------------------------
// Kernel 1: transpose+convert the 3 weights [1024][512] f32 -> Wt bf16 [512][1024]
// ---------------------------------------------------------------------------
__global__ __launch_bounds__(256) void prep_w(const float* __restrict__ Wq,
                                              const float* __restrict__ Wk,
                                              const float* __restrict__ Wv,
                                              unsigned short* __restrict__ wt) {
  int z = blockIdx.z;
  const float* W = (z == 0) ? Wq : ((z == 1) ? Wk : Wv);
  unsigned short* o = wt + (size_t)z * DD * FF;
  __shared__ __align__(16) float t[32][33];
  int k0 = blockIdx.x * 32, n0 = blockIdx.y * 32;
  int tid = threadIdx.x;
  int r = tid >> 3, c4 = (tid & 7) * 4;
  f32x4 v = *(const f32x4*)(W + (size_t)(k0 + r) * DD + n0 + c4);
  t[r][c4 + 0] = v[0]; t[r][c4 + 1] = v[1]; t[r][c4 + 2] = v[2]; t[r][c4 + 3] = v[3];
  __syncthreads();
  s16x4 h;
  h[0] = (short)f2bf(t[c4 + 0][r]);
  h[1] = (short)f2bf(t[c4 + 1][r]);
  h[2] = (short)f2bf(t[c4 + 2][r]);
  h[3] = (short)f2bf(t[c4 + 3][r]);
  *(s16x4*)(o + (size_t)(n0 + r) * FF + k0 + c4) = h;
}

// ---------------------------------------------------------------------------
// Kernel 2: GEMM (m97 structure): C[16384][512] = xb[16384][1024] @ W + bias
//   128x128 tile, BK=32, 4 waves (2x2), global_load_lds width 16.
//   z=0: q (scaled by log2e/sqrt(512)), z=1: k, z=2: v stored TRANSPOSED [B][512][S]
//   v epilogue: per-wave LDS transpose -> 16B coalesced stores.
// ---------------------------------------------------------------------------
__global__ __launch_bounds__(256, 2) void gemm_qkv(
    const unsigned short* __restrict__ xb, const unsigned short* __restrict__ wt,
    const float* __restrict__ bq, const float* __restrict__ bk, const float* __restrict__ bv,
    unsigned short* __restrict__ qo, unsigned short* __restrict__ ko,
    unsigned short* __restrict__ vto) {
  const int wsel = blockIdx.z;
  const unsigned short* W = wt + (size_t)wsel * DD * FF;
  const float* bias = (wsel == 0) ? bq : ((wsel == 1) ? bk : bv);
  const int m0 = blockIdx.x * 128, n0 = blockIdx.y * 128;

  // union: main loop uses Al(8K)+Bl(8K); v-epilogue reuses as 4x64x72 u16 transpose buf
  __shared__ __align__(16) char smem[36864];
  unsigned short* Al = (unsigned short*)smem;
  unsigned short* Bl = (unsigned short*)(smem + 8192);

  const int tid = threadIdx.x;
  const int lane = tid & 63, wv = tid >> 6;
  const int wr = wv >> 1, wc = wv & 1;
  const int l15 = lane & 15, lg = lane >> 4;

  const f32x4 fzero = {0.f, 0.f, 0.f, 0.f};
  f32x4 acc[4][4];
#pragma unroll
  for (int i = 0; i < 4; ++i)
#pragma unroll
    for (int j = 0; j < 4; ++j) acc[i][j] = fzero;

  for (int k0 = 0; k0 < FF; k0 += 32) {
#pragma unroll
    for (int is = 0; is < 2; ++is) {
      int chunk = (is * 4 + wv) * 64;       // 64 lane-16B units
      int lin = (chunk + lane) * 8;         // elements
      int r = lin >> 5, c = lin & 31;
      async16(xb + (size_t)(m0 + r) * FF + k0 + c, (char*)Al + (size_t)chunk * 16);
      async16(W + (size_t)(n0 + r) * FF + k0 + c, (char*)Bl + (size_t)chunk * 16);
    }
    __syncthreads();
    s16x8 af[4], bf[4];
#pragma unroll
    for (int mi = 0; mi < 4; ++mi)
      af[mi] = *(const s16x8*)(&Al[(wr * 64 + mi * 16 + l15) * 32 + lg * 8]);
#pragma unroll
    for (int ni = 0; ni < 4; ++ni)
      bf[ni] = *(const s16x8*)(&Bl[(wc * 64 + ni * 16 + l15) * 32 + lg * 8]);
#pragma unroll
    for (int mi = 0; mi < 4; ++mi)
#pragma unroll
      for (int ni = 0; ni < 4; ++ni)
        acc[mi][ni] = __builtin_amdgcn_mfma_f32_16x16x32_bf16(af[mi], bf[ni], acc[mi][ni], 0, 0, 0);
    __syncthreads();
  }

  const float QS = 0.0637583894f;  // (1/sqrt(512)) * log2(e)
  if (wsel == 2) {
    // transpose 64x64 wave tile through per-wave LDS, then 16B coalesced stores
    unsigned short* Tw = (unsigned short*)smem + (size_t)wv * 64 * 72;
#pragma unroll
    for (int ni = 0; ni < 4; ++ni) {
      int cl = ni * 16 + l15;
      float bvv = bias[n0 + wc * 64 + cl];
#pragma unroll
      for (int mi = 0; mi < 4; ++mi)
#pragma unroll
        for (int j = 0; j < 4; ++j)
          Tw[cl * 72 + mi * 16 + lg * 4 + j] = f2bf(acc[mi][ni][j] + bvv);
    }
    asm volatile("s_waitcnt lgkmcnt(0)" ::: "memory");
    const int bb = (m0 + wr * 64) >> 11;       // batch (64-row tile never straddles)
    const int sb = (m0 + wr * 64) & 2047;      // seq base
    const int cb = n0 + wc * 64;               // d base
#pragma unroll
    for (int p = 0; p < 8; ++p) {
      int cl = p * 8 + (lane >> 3);
      int sl = (lane & 7) * 8;
      s16x8 vv = *(const s16x8*)(Tw + cl * 72 + sl);
      *(s16x8*)(vto + ((size_t)(bb * DD + cb + cl)) * SS + sb + sl) = vv;
    }
  } else {
    unsigned short* o = wsel ? ko : qo;
#pragma unroll
    for (int ni = 0; ni < 4; ++ni) {
      int cg = n0 + wc * 64 + ni * 16 + l15;
      float bvv = bias[cg];
#pragma unroll
      for (int mi = 0; mi < 4; ++mi) {
#pragma unroll
        for (int j = 0; j < 4; ++j) {
          int rg = m0 + wr * 64 + mi * 16 + lg * 4 + j;
          float val = acc[mi][ni][j] + bvv;
          if (wsel == 0) val *= QS;
          o[(size_t)rg * DD + cg] = f2bf(val);
        }
      }
    }
  }
}

// ---------------------------------------------------------------------------
// Kernel 3: causal flash attention — round-3 staged structure + T14 async-STAGE:
//   prefetch tile t+1 into registers right after the LDS-ready barrier so the
//   L2 latency hides under tile t's MFMA/softmax; only ds_writes sit between
//   the two barriers. Per-lane partial l-sum (reduced once in epilogue).
//   Grid (32, 8, 2): z = vhalf; z=1 mirrors qt so per-CU work is balanced.
// ---------------------------------------------------------------------------
__global__ __launch_bounds__(256, 2) void attn(const unsigned short* __restrict__ qg,
                                               const unsigned short* __restrict__ kgl,
                                               const unsigned short* __restrict__ vtg,
                                               float* __restrict__ out) {
  const int b = blockIdx.y;
  const int vhalf = blockIdx.z;
  const int qt = (vhalf == 0) ? blockIdx.x : (31 - blockIdx.x);
  const int q0 = qt * 64;

  __shared__ __align__(16) unsigned short Kl[32 * 520];   // 32 keys x 512 d, +8 pad
  __shared__ __align__(16) unsigned short Vl[256 * 40];   // 256 vcols x 32 keys, +8 pad
  __shared__ __align__(16) unsigned short Pl[4 * 16 * 40];// per-wave P bounce

  const int tid = threadIdx.x;
  const int lane = tid & 63, w = tid >> 6;
  const int l15 = lane & 15, lg = lane >> 4;

  // per-thread staging geometry (constant across tiles)
  const int kR = tid >> 6, kC = (tid & 63) * 8;           // K: 4 rows/iter chunk
  const int vN = tid >> 2, vC = (tid & 3) * 8;            // V: 64 rows/iter chunk
  const unsigned short* kbase = kgl + ((size_t)(b * SS + kR)) * DD + kC;
  const unsigned short* vbase = vtg + ((size_t)(b * DD + vhalf * 256 + vN)) * SS + vC;

  // preload Q fragments (16 k-chunks of 32)
  s16x8 qf[16];
  {
    const unsigned short* qp = qg + ((size_t)(b * SS + q0 + w * 16 + l15)) * DD + lg * 8;
#pragma unroll
    for (int kk = 0; kk < 16; ++kk) qf[kk] = *(const s16x8*)(qp + kk * 32);
  }

  const f32x4 fzero = {0.f, 0.f, 0.f, 0.f};
  f32x4 oacc[16];
#pragma unroll
  for (int n = 0; n < 16; ++n) oacc[n] = fzero;
  float mrun[4], lsum[4];
#pragma unroll
  for (int i = 0; i < 4; ++i) { mrun[i] = -__builtin_inff(); lsum[i] = 0.f; }

  const int nt = qt * 2 + 2;  // kv tiles of 32 covering keys <= q0+63

  // prefetch tile 0 into registers
  f32x4 kreg[8], vreg[4];
#pragma unroll
  for (int it = 0; it < 8; ++it)
    kreg[it] = *(const f32x4*)(kbase + (size_t)(it * 4) * DD);
#pragma unroll
  for (int it = 0; it < 4; ++it)
    vreg[it] = *(const f32x4*)(vbase + (size_t)(it * 64) * SS);

  for (int t = 0; t < nt; ++t) {
    const int kv0 = t * 32;
    __syncthreads();  // LDS free (prev tile's compute done)
    // regs -> LDS (compiler waits vmcnt for kreg/vreg deps automatically)
#pragma unroll
    for (int it = 0; it < 8; ++it)
      *(f32x4*)(&Kl[(kR + it * 4) * 520 + kC]) = kreg[it];
#pragma unroll
    for (int it = 0; it < 4; ++it)
      *(f32x4*)(&Vl[(vN + it * 64) * 40 + vC]) = vreg[it];
    __syncthreads();  // LDS ready

    // issue next tile's global loads; latency hides under this tile's compute
    if (t + 1 < nt) {
      const int nkv = kv0 + 32;
#pragma unroll
      for (int it = 0; it < 8; ++it)
        kreg[it] = *(const f32x4*)(kbase + (size_t)(nkv + it * 4) * DD);
#pragma unroll
      for (int it = 0; it < 4; ++it)
        vreg[it] = *(const f32x4*)(vbase + (size_t)(it * 64) * SS + nkv);
    }

    // ---- S = Q @ K^T  (2 fragments of 16x16, reduce over 512)
    f32x4 s0 = fzero, s1 = fzero;
#pragma unroll
    for (int kk = 0; kk < 16; ++kk) {
      s16x8 b0 = *(const s16x8*)(&Kl[l15 * 520 + kk * 32 + lg * 8]);
      s16x8 b1 = *(const s16x8*)(&Kl[(16 + l15) * 520 + kk * 32 + lg * 8]);
      s0 = __builtin_amdgcn_mfma_f32_16x16x32_bf16(qf[kk], b0, s0, 0, 0, 0);
      s1 = __builtin_amdgcn_mfma_f32_16x16x32_bf16(qf[kk], b1, s1, 0, 0, 0);
    }

    // ---- causal mask (rows = q0+16w+4*lg+i, cols = kv0 + {0,16} + l15)
    const int rowb = q0 + w * 16 + lg * 4;
    if (kv0 + 31 > q0 + w * 16) {
#pragma unroll
      for (int i = 0; i < 4; ++i) {
        int rg = rowb + i;
        if (kv0 + l15 > rg)      s0[i] = -__builtin_inff();
        if (kv0 + 16 + l15 > rg) s1[i] = -__builtin_inff();
      }
    }

    // ---- online softmax (exp2 domain; scale folded into q at GEMM)
    float corr[4];
#pragma unroll
    for (int i = 0; i < 4; ++i) {
      float tm = fmaxf(s0[i], s1[i]);
      tm = fmaxf(tm, __shfl_xor(tm, 1));
      tm = fmaxf(tm, __shfl_xor(tm, 2));
      tm = fmaxf(tm, __shfl_xor(tm, 4));
      tm = fmaxf(tm, __shfl_xor(tm, 8));
      float mo = mrun[i];
      float mn = fmaxf(mo, tm);
      mrun[i] = mn;
      float c = __builtin_amdgcn_exp2f(mo - mn);
      float p0 = __builtin_amdgcn_exp2f(s0[i] - mn);
      float p1 = __builtin_amdgcn_exp2f(s1[i] - mn);
      lsum[i] = lsum[i] * c + p0 + p1;   // per-lane partial; reduced in epilogue
      corr[i] = c;
      Pl[w * 640 + (lg * 4 + i) * 40 + l15] = f2bf(p0);
      Pl[w * 640 + (lg * 4 + i) * 40 + 16 + l15] = f2bf(p1);
    }

    // ---- rescale O
#pragma unroll
    for (int n = 0; n < 16; ++n) {
      oacc[n][0] *= corr[0]; oacc[n][1] *= corr[1];
      oacc[n][2] *= corr[2]; oacc[n][3] *= corr[3];
    }

    // ---- PV: O += P @ V  (P via wave-private LDS bounce)
    asm volatile("s_waitcnt lgkmcnt(0)" ::: "memory");
    s16x8 pa = *(const s16x8*)(&Pl[w * 640 + l15 * 40 + lg * 8]);
#pragma unroll
    for (int n = 0; n < 16; ++n) {
      s16x8 vv = *(const s16x8*)(&Vl[(n * 16 + l15) * 40 + lg * 8]);
      oacc[n] = __builtin_amdgcn_mfma_f32_16x16x32_bf16(pa, vv, oacc[n], 0, 0, 0);
    }
  }

  // ---- epilogue: reduce l across the 16-lane group, normalize, store
  float inv[4];
#pragma unroll
  for (int i = 0; i < 4; ++i) {
    float rs = lsum[i];
    rs += __shfl_xor(rs, 1);
    rs += __shfl_xor(rs, 2);
    rs += __shfl_xor(rs, 4);
    rs += __shfl_xor(rs, 8);
    inv[i] = 1.0f / rs;
  }
  size_t obase = ((size_t)(b * SS + q0 + w * 16 + lg * 4)) * 1536 + 1024 + vhalf * 256;
#pragma unroll
  for (int n = 0; n < 16; ++n) {
#pragma unroll
    for (int i = 0; i < 4; ++i) {
      out[obase + (size_t)i * 1536 + n * 16 + l15] = oacc[n][i] * inv[i];
    }
  }
}

// ---------------------------------------------------------------------------
// launch
// ---------------------------------------------------------------------------
extern "C" void kernel_launch(void* const* d_in, const int* in_sizes, int n_in,
                              void* d_out, int out_size, void* d_ws, size_t ws_size,
                              hipStream_t stream) {
  (void)in_sizes; (void)n_in; (void)out_size; (void)ws_size;
  const float* x  = (const float*)d_in[0];
  const float* Wq = (const float*)d_in[1];
  const float* bq = (const float*)d_in[2];
  const float* Wk = (const float*)d_in[3];
  const float* bk = (const float*)d_in[4];
  const float* Wv = (const float*)d_in[5];
  const float* bv = (const float*)d_in[6];
  float* out = (float*)d_out;

  // workspace layout (total ~83 MiB)
  char* ws = (char*)d_ws;
  unsigned short* xb  = (unsigned short*)(ws);                       // 32 MiB
  unsigned short* wt  = (unsigned short*)(ws + 33554432);            // 3 MiB
  unsigned short* qw  = (unsigned short*)(ws + 33554432 + 3145728);  // 16 MiB
  unsigned short* kw  = qw + (size_t)16384 * 512;                    // 16 MiB
  unsigned short* vtw = kw + (size_t)16384 * 512;                    // 16 MiB (transposed [B][512][S])

  convert_x<<<16384, 256, 0, stream>>>(x, out, xb);
  prep_w<<<dim3(32, 16, 3), 256, 0, stream>>>(Wq, Wk, Wv, wt);
  gemm_qkv<<<dim3(128, 4, 3), 256, 0, stream>>>(xb, wt, bq, bk, bv, qw, kw, vtw);
  attn<<<dim3(32, 8, 2), 256, 0, stream>>>(qw, kw, vtw, out);
}